// Round 1
// baseline (328.614 us; speedup 1.0000x reference)
//
#include <hip/hip_runtime.h>
#include <math.h>

#define BS 8
#define CCH 4096
#define SP 891
#define NSLICE (BS*CCH)   // 32768 slices of 891 floats
#define DD (SP*BS)        // 7128

// ---------- per-slice squared norms (level-independent) ----------
__global__ void k_slicenorm(const float* __restrict__ X, float* __restrict__ sn2) {
  int slice = blockIdx.x * 4 + (threadIdx.x >> 6);
  int lane = threadIdx.x & 63;
  if (slice >= NSLICE) return;
  const float* p = X + (size_t)slice * SP;
  float acc = 0.f;
  for (int s = lane; s < SP; s += 64) { float v = p[s]; acc += v * v; }
  for (int o = 32; o; o >>= 1) acc += __shfl_xor(acc, o, 64);
  if (lane == 0) sn2[slice] = acc;
}

// ---------- cluster histogram ----------
__global__ void k_hist(const int* __restrict__ im2c, int* __restrict__ counts) {
  int ch = blockIdx.x * blockDim.x + threadIdx.x;
  if (ch < CCH) atomicAdd(&counts[im2c[ch]], 1);
}

// ---------- exclusive prefix (K<=64, serial is fine) ----------
__global__ void k_prefix(const int* __restrict__ counts, int* __restrict__ offsets, int K) {
  if (threadIdx.x == 0) {
    int s = 0;
    for (int c = 0; c < K; c++) { offsets[c] = s; s += counts[c]; }
  }
}

// ---------- sorted member lists: one wave per cluster, ballot-append ----------
__global__ void k_members(const int* __restrict__ im2c, const int* __restrict__ offsets,
                          int* __restrict__ members) {
  int c = blockIdx.x;
  int lane = threadIdx.x; // blockDim = 64
  int base = offsets[c];
  int cnt = 0;
  for (int chunk = 0; chunk < CCH; chunk += 64) {
    int ch = chunk + lane;
    bool m = (im2c[ch] == c);
    unsigned long long mk = __ballot(m);
    int pos = __popcll(mk & ((1ull << lane) - 1ull));
    if (m) members[base + cnt + pos] = ch;
    cnt += __popcll(mk);
  }
}

// ---------- row tables (slice offsets per row) + row squared norms ----------
__global__ void k_rows(const int* __restrict__ counts, const int* __restrict__ offsets,
                       const int* __restrict__ members, const float* __restrict__ sn2,
                       int* __restrict__ rowOff, float* __restrict__ rn2) {
  int c = blockIdx.x;
  int n = counts[c], base = offsets[c];
  for (int r = threadIdx.x; r < n; r += blockDim.x) {
    float s2 = 0.f;
    for (int q = 0; q < 8; q++) {
      int p = 8 * r + q;
      int b = p / n, j = p - b * n;
      int sid = b * CCH + members[base + j];
      rowOff[(size_t)(base + r) * 8 + q] = sid * SP;
      s2 += sn2[sid];
    }
    rn2[base + r] = s2;
  }
}

// ---------- gather rep matrix Brep[8][SP][K] (k-major, c' contiguous) ----------
__global__ void k_brep(const float* __restrict__ X, const int* __restrict__ counts,
                       const int* __restrict__ offsets, const int* __restrict__ members,
                       float* __restrict__ Brep, int K) {
  int total = 8 * SP * K;
  for (int t = blockIdx.x * blockDim.x + threadIdx.x; t < total; t += gridDim.x * blockDim.x) {
    int cc = t % K;
    int s = (t / K) % SP;
    int q = t / (K * SP);
    int n = counts[cc];
    float v = 0.f;
    if (n > 0) {
      int b = q / n, j = q - b * n;
      v = X[(size_t)(b * CCH + members[offsets[cc] + j]) * SP + s];
    }
    Brep[t] = v;
  }
}

// ---------- main GEMM: P8[q][row][c'] = sum_s X[slice(row,q)][s] * Brep[q][s][c'] ----------
template<int N>
__global__ __launch_bounds__(256) void k_gemm(const float* __restrict__ X,
                                              const float* __restrict__ Brep,
                                              const int* __restrict__ rowOff,
                                              float* __restrict__ P8) {
  constexpr int TM = 64, KC = 64;
  constexpr int TX = N / 4;        // 16 (N=64) or 4 (N=16)
  constexpr int TY = 256 / TX;     // 16 or 64
  constexpr int MR = TM / TY;      // 4 or 1
  __shared__ float As[TM][KC + 1]; // +1 pad: conflict-free column reads
  __shared__ float Bs[KC][N];
  __shared__ int rbase[TM];
  const int q = blockIdx.y;
  const int row0 = blockIdx.x * TM;
  const int tid = threadIdx.x;
  if (tid < TM) rbase[tid] = rowOff[(size_t)(row0 + tid) * 8 + q];
  __syncthreads();
  const int tx = tid % TX, ty = tid / TX;
  float acc[MR][4];
  for (int i = 0; i < MR; i++)
    for (int j = 0; j < 4; j++) acc[i][j] = 0.f;

  for (int k0 = 0; k0 < SP; k0 += KC) {
    #pragma unroll
    for (int i = 0; i < (TM * KC) / 256; i++) {
      int idx = i * 256 + tid;
      int r = idx / KC, k = idx % KC;
      int s = k0 + k;
      As[r][k] = (s < SP) ? X[(size_t)rbase[r] + s] : 0.f;
    }
    #pragma unroll
    for (int i = 0; i < (KC * N) / 256; i++) {
      int idx = i * 256 + tid;
      int cc = idx % N, k = idx / N;
      int s = k0 + k;
      Bs[k][cc] = (s < SP) ? Brep[(size_t)(q * SP + s) * N + cc] : 0.f;
    }
    __syncthreads();
    #pragma unroll
    for (int k = 0; k < KC; k++) {
      float a[MR];
      #pragma unroll
      for (int i = 0; i < MR; i++) a[i] = As[ty * MR + i][k];
      const float4 b = *reinterpret_cast<const float4*>(&Bs[k][tx * 4]);
      #pragma unroll
      for (int i = 0; i < MR; i++) {
        acc[i][0] += a[i] * b.x; acc[i][1] += a[i] * b.y;
        acc[i][2] += a[i] * b.z; acc[i][3] += a[i] * b.w;
      }
    }
    __syncthreads();
  }
  #pragma unroll
  for (int i = 0; i < MR; i++) {
    int r = row0 + ty * MR + i;
    float4* dst = reinterpret_cast<float4*>(&P8[((size_t)q * CCH + r) * N + tx * 4]);
    *dst = make_float4(acc[i][0], acc[i][1], acc[i][2], acc[i][3]);
  }
}

// ---------- per-cluster epilogue: conc, logsumexp, cluster loss ----------
template<int K>
__global__ __launch_bounds__(256) void k_finalize(const float* __restrict__ P8,
                                                  const float* __restrict__ rn2,
                                                  const int* __restrict__ counts,
                                                  const int* __restrict__ offsets,
                                                  double* __restrict__ clLoss) {
  __shared__ float pcc[4096];
  __shared__ double red[256];
  __shared__ double s_conc;
  const int c = blockIdx.x;
  const int n = counts[c], base = offsets[c];
  const int tid = threadIdx.x;
  if (n <= 1) { if (tid == 0) clLoss[c] = 0.0; return; }

  // phase 1: P[r][c] and conc
  double t = 0.0;
  float rn2_0 = rn2[base];
  for (int r = tid; r < n; r += 256) {
    float s = 0.f;
    for (int q = 0; q < 8; q++) s += P8[((size_t)q * CCH + base + r) * K + c];
    pcc[r] = s;
    float d2 = rn2[base + r] - 2.f * s + rn2_0;
    t += sqrt((double)(d2 > 0.f ? d2 : 0.f));
  }
  red[tid] = t; __syncthreads();
  for (int o = 128; o; o >>= 1) { if (tid < o) red[tid] += red[tid + o]; __syncthreads(); }
  if (tid == 0) s_conc = red[0] / ((double)n * log((double)n + 10.0));
  __syncthreads();
  const float invc = (float)(1.0 / s_conc);

  // phase 2: per-row logsumexp over K logits; lanes grouped K-wide
  const int wave = tid >> 6, lane = tid & 63;
  constexpr int RPW = 64 / K;       // rows handled per wave iteration
  const int sub = lane / K;
  const int cc = lane % K;
  double acc = 0.0;
  for (int r0 = wave * RPW; r0 < n; r0 += 4 * RPW) {
    int r = r0 + sub;
    bool valid = (r < n);
    float lg = -3.0e38f;
    if (valid) {
      float s = 0.f;
      for (int q = 0; q < 8; q++) s += P8[((size_t)q * CCH + base + r) * K + cc];
      lg = s * invc;
    }
    float m = lg;
    #pragma unroll
    for (int o = K / 2; o; o >>= 1) m = fmaxf(m, __shfl_xor(m, o, K));
    float e = valid ? expf(lg - m) : 0.f;
    float se = e;
    #pragma unroll
    for (int o = K / 2; o; o >>= 1) se += __shfl_xor(se, o, K);
    if (valid && cc == 0) {
      float den = m + logf(se);
      acc += (double)den - (double)(pcc[r] * invc);
    }
  }
  red[tid] = acc; __syncthreads();
  for (int o = 128; o; o >>= 1) { if (tid < o) red[tid] += red[tid + o]; __syncthreads(); }
  if (tid == 0) clLoss[c] = red[0] / (double)n;
}

// ---------- final: sum cluster losses, scale, write the two outputs ----------
__global__ void k_final(const double* __restrict__ cl0, const double* __restrict__ cl1,
                        float* __restrict__ out) {
  if (threadIdx.x == 0) {
    double s0 = 0.0, s1 = 0.0;
    for (int i = 0; i < 64; i++) s0 += cl0[i];
    for (int i = 0; i < 16; i++) s1 += cl1[i];
    out[0] = (float)(s0 / 4096.0);          // loss_node / C
    out[1] = (float)(s1 / (2.0 * 4096.0));  // (loss - loss_node) / (len(N_KM)*C)
  }
}

extern "C" void kernel_launch(void* const* d_in, const int* in_sizes, int n_in,
                              void* d_out, int out_size, void* d_ws, size_t ws_size,
                              hipStream_t stream) {
  const float* X = (const float*)d_in[0];
  const int* im0 = (const int*)d_in[1];
  const int* im1 = (const int*)d_in[2];
  float* out = (float*)d_out;

  char* w = (char*)d_ws;
  auto alloc = [&](size_t bytes) -> char* {
    char* p = w; w += (bytes + 255) & ~(size_t)255; return p;
  };
  int*    cnt0  = (int*)alloc(64 * 4);
  int*    off0  = (int*)alloc(64 * 4);
  int*    cnt1  = (int*)alloc(16 * 4);
  int*    off1  = (int*)alloc(16 * 4);
  int*    mem0  = (int*)alloc(CCH * 4);
  int*    mem1  = (int*)alloc(CCH * 4);
  float*  sn2   = (float*)alloc((size_t)NSLICE * 4);
  int*    rows0 = (int*)alloc((size_t)CCH * 8 * 4);
  int*    rows1 = (int*)alloc((size_t)CCH * 8 * 4);
  float*  rn2_0 = (float*)alloc((size_t)CCH * 4);
  float*  rn2_1 = (float*)alloc((size_t)CCH * 4);
  float*  Brep0 = (float*)alloc((size_t)8 * SP * 64 * 4);
  float*  Brep1 = (float*)alloc((size_t)8 * SP * 16 * 4);
  float*  P8_0  = (float*)alloc((size_t)8 * CCH * 64 * 4);
  float*  P8_1  = (float*)alloc((size_t)8 * CCH * 16 * 4);
  double* cl0   = (double*)alloc(64 * 8);
  double* cl1   = (double*)alloc(16 * 8);

  hipMemsetAsync(cnt0, 0, 64 * 4, stream);
  hipMemsetAsync(cnt1, 0, 16 * 4, stream);

  k_slicenorm<<<NSLICE / 4, 256, 0, stream>>>(X, sn2);
  k_hist<<<CCH / 256, 256, 0, stream>>>(im0, cnt0);
  k_hist<<<CCH / 256, 256, 0, stream>>>(im1, cnt1);
  k_prefix<<<1, 64, 0, stream>>>(cnt0, off0, 64);
  k_prefix<<<1, 64, 0, stream>>>(cnt1, off1, 16);
  k_members<<<64, 64, 0, stream>>>(im0, off0, mem0);
  k_members<<<16, 64, 0, stream>>>(im1, off1, mem1);
  k_rows<<<64, 256, 0, stream>>>(cnt0, off0, mem0, sn2, rows0, rn2_0);
  k_rows<<<16, 256, 0, stream>>>(cnt1, off1, mem1, sn2, rows1, rn2_1);
  k_brep<<<512, 256, 0, stream>>>(X, cnt0, off0, mem0, Brep0, 64);
  k_brep<<<512, 256, 0, stream>>>(X, cnt1, off1, mem1, Brep1, 16);
  k_gemm<64><<<dim3(CCH / 64, 8), 256, 0, stream>>>(X, Brep0, rows0, P8_0);
  k_gemm<16><<<dim3(CCH / 64, 8), 256, 0, stream>>>(X, Brep1, rows1, P8_1);
  k_finalize<64><<<64, 256, 0, stream>>>(P8_0, rn2_0, cnt0, off0, cl0);
  k_finalize<16><<<16, 256, 0, stream>>>(P8_1, rn2_1, cnt1, off1, cl1);
  k_final<<<1, 64, 0, stream>>>(cl0, cl1, out);
}

// Round 2
// 199.275 us; speedup vs baseline: 1.6490x; 1.6490x over previous
//
#include <hip/hip_runtime.h>
#include <math.h>

#define CCH 4096
#define SP 891
#define SPAD 896

typedef __attribute__((ext_vector_type(8))) short short8;
typedef __attribute__((ext_vector_type(4))) float f32x4;

__device__ __forceinline__ unsigned int pack_bf2(float a, float b) {
  unsigned int ua = __builtin_bit_cast(unsigned int, a);
  unsigned int ub = __builtin_bit_cast(unsigned int, b);
  ua = (ua + 0x7fffu + ((ua >> 16) & 1u)) >> 16;
  ub = (ub + 0x7fffu + ((ub >> 16) & 1u)) >> 16;
  return ua | (ub << 16);
}

// ---------- cluster histogram ----------
__global__ void k_hist(const int* __restrict__ im2c, int* __restrict__ counts) {
  int ch = blockIdx.x * blockDim.x + threadIdx.x;
  if (ch < CCH) atomicAdd(&counts[im2c[ch]], 1);
}

// ---------- exclusive prefix ----------
__global__ void k_prefix(const int* __restrict__ counts, int* __restrict__ offsets, int K) {
  if (threadIdx.x == 0) {
    int s = 0;
    for (int c = 0; c < K; c++) { offsets[c] = s; s += counts[c]; }
  }
}

// ---------- sorted member lists ----------
__global__ void k_members(const int* __restrict__ im2c, const int* __restrict__ offsets,
                          int* __restrict__ members) {
  int c = blockIdx.x;
  int lane = threadIdx.x; // blockDim = 64
  int base = offsets[c];
  int cnt = 0;
  for (int chunk = 0; chunk < CCH; chunk += 64) {
    int ch = chunk + lane;
    bool m = (im2c[ch] == c);
    unsigned long long mk = __ballot(m);
    int pos = __popcll(mk & ((1ull << lane) - 1ull));
    if (m) members[base + cnt + pos] = ch;
    cnt += __popcll(mk);
  }
}

// ---------- per-row slice-id tables ----------
__global__ void k_rowsid(const int* __restrict__ counts, const int* __restrict__ offsets,
                         const int* __restrict__ members, int* __restrict__ rowSid) {
  int c = blockIdx.x;
  int n = counts[c], base = offsets[c];
  for (int r = threadIdx.x; r < n; r += blockDim.x) {
    for (int q = 0; q < 8; q++) {
      int p = 8 * r + q;
      int b = p / n, j = p - b * n;
      rowSid[(size_t)(base + r) * 8 + q] = b * CCH + members[base + j];
    }
  }
}

// ---------- gather rep matrix as bf16, padded to SPAD: Brep[q][c'][SPAD] ----------
__global__ void k_brep(const float* __restrict__ X, const int* __restrict__ counts,
                       const int* __restrict__ offsets, const int* __restrict__ members,
                       unsigned int* __restrict__ Brep32, int K) {
  int total = 8 * K * (SPAD / 2);
  for (int t = blockIdx.x * blockDim.x + threadIdx.x; t < total; t += gridDim.x * blockDim.x) {
    int s2 = (t % (SPAD / 2)) * 2;
    int cc = (t / (SPAD / 2)) % K;
    int q = t / ((SPAD / 2) * K);
    int n = counts[cc];
    int b = q / n, j = q - b * n;
    const float* src = X + (size_t)(b * CCH + members[offsets[cc] + j]) * SP;
    float v0 = (s2 < SP) ? src[s2] : 0.f;
    float v1 = (s2 + 1 < SP) ? src[s2 + 1] : 0.f;
    Brep32[t] = pack_bf2(v0, v1);
  }
}

// ---------- MFMA GEMM body: P8[q][row][c'] = dot(slice(row,q), rep_seg_q(c')) ----------
template<int TM, int N, bool SN2>
__device__ __forceinline__ void gemm_body(short* As_, short* Bs_, int* s_sid,
    int bx, int q, const float* __restrict__ X, const unsigned short* __restrict__ Brep,
    const int* __restrict__ rowSid, float* __restrict__ P8, float* __restrict__ sn2) {
  constexpr int KC = 64;
  constexpr int NSTEP = SPAD / KC;   // 14
  constexpr int LDAB = 72;           // padded LDS row (bf16 elems), 144B
  constexpr int NCS = N / 16;        // col strips
  constexpr int WM = 4 / NCS;        // waves along M
  constexpr int FM = TM / (16 * WM); // M-frags per wave
  constexpr int AI = TM / 8;         // A staging iters (pairs)
  constexpr int BI = (N * 8 + 255) / 256;

  const int row0 = bx * TM;
  const int tid = threadIdx.x;
  if (tid < TM) s_sid[tid] = rowSid[(size_t)(row0 + tid) * 8 + q];
  __syncthreads();

  const int l = tid & 63, w = tid >> 6;
  const int cbase = (w % NCS) * 16;
  const int mbase = (w / NCS) * (FM * 16);
  const int lrow = l & 15;
  const int lk = (l >> 4) * 8;

  // hoisted per-thread staging bases
  int my_sb[AI];
  #pragma unroll
  for (int i = 0; i < AI; i++) my_sb[i] = s_sid[(i * 256 + tid) >> 5] * SP;
  const unsigned short* bp[BI];
  #pragma unroll
  for (int i = 0; i < BI; i++) {
    int idx = i * 256 + tid;
    int brow = (idx < N * 8) ? (idx >> 3) : 0;
    bp[i] = Brep + (size_t)(q * N + brow) * SPAD + (idx & 7) * 8;
  }

  f32x4 acc[FM];
  #pragma unroll
  for (int m = 0; m < FM; m++) acc[m] = (f32x4){0.f, 0.f, 0.f, 0.f};
  float acc2[AI];
  #pragma unroll
  for (int i = 0; i < AI; i++) acc2[i] = 0.f;

  float ar0[AI], ar1[AI];
  uint4 br[BI];

  auto LOADG = [&](int t) {
    int k0 = t * KC;
    #pragma unroll
    for (int i = 0; i < AI; i++) {
      int idx = i * 256 + tid;
      int k = k0 + ((idx & 31) << 1);
      ar0[i] = (k < SP) ? X[my_sb[i] + k] : 0.f;
      ar1[i] = (k + 1 < SP) ? X[my_sb[i] + k + 1] : 0.f;
    }
    #pragma unroll
    for (int i = 0; i < BI; i++) {
      int idx = i * 256 + tid;
      if (idx < N * 8) br[i] = *(const uint4*)(bp[i] + k0);
    }
  };
  auto STORE = [&](int buf) {
    #pragma unroll
    for (int i = 0; i < AI; i++) {
      int idx = i * 256 + tid;
      int arow = idx >> 5, k2 = (idx & 31) << 1;
      *(unsigned int*)(As_ + (buf * TM + arow) * LDAB + k2) = pack_bf2(ar0[i], ar1[i]);
      if (SN2) acc2[i] += ar0[i] * ar0[i] + ar1[i] * ar1[i];
    }
    #pragma unroll
    for (int i = 0; i < BI; i++) {
      int idx = i * 256 + tid;
      if (idx < N * 8)
        *(uint4*)(Bs_ + (buf * N + (idx >> 3)) * LDAB + (idx & 7) * 8) = br[i];
    }
  };

  LOADG(0); STORE(0); __syncthreads();
  for (int t = 0; t < NSTEP; ++t) {
    int buf = t & 1;
    if (t + 1 < NSTEP) LOADG(t + 1);
    #pragma unroll
    for (int kk = 0; kk < 2; ++kk) {
      short8 bfr = *(const short8*)(Bs_ + (buf * N + cbase + lrow) * LDAB + lk + kk * 32);
      #pragma unroll
      for (int m = 0; m < FM; ++m) {
        short8 afr = *(const short8*)(As_ + (buf * TM + mbase + m * 16 + lrow) * LDAB + lk + kk * 32);
        acc[m] = __builtin_amdgcn_mfma_f32_16x16x32_bf16(afr, bfr, acc[m], 0, 0, 0);
      }
    }
    if (t + 1 < NSTEP) { __syncthreads(); STORE(buf ^ 1); __syncthreads(); }
  }

  #pragma unroll
  for (int m = 0; m < FM; m++) {
    #pragma unroll
    for (int r = 0; r < 4; r++) {
      int row = row0 + mbase + m * 16 + (l >> 4) * 4 + r;
      P8[((size_t)q * CCH + row) * N + cbase + lrow] = acc[m][r];
    }
  }
  if (SN2) {
    #pragma unroll
    for (int i = 0; i < AI; i++) {
      float s = acc2[i];
      for (int o = 16; o; o >>= 1) s += __shfl_xor(s, o, 32);
      int idx = i * 256 + tid;
      if ((idx & 31) == 0) sn2[s_sid[idx >> 5]] = s;
    }
  }
}

__global__ __launch_bounds__(256) void k_gemm_fused(const float* __restrict__ X,
    const unsigned short* __restrict__ Brep0, const unsigned short* __restrict__ Brep1,
    const int* __restrict__ rowSid0, const int* __restrict__ rowSid1,
    float* __restrict__ P8_0, float* __restrict__ P8_1, float* __restrict__ sn2) {
  __shared__ __align__(16) short lds[13824]; // max(L0: 4608+9216, L1: 9216+2304)
  __shared__ int s_sid[64];
  int q = blockIdx.y;
  if (blockIdx.x < 128) {
    gemm_body<32, 64, true>(lds, lds + 2 * 32 * 72, s_sid, blockIdx.x, q, X, Brep0, rowSid0, P8_0, sn2);
  } else {
    gemm_body<64, 16, false>(lds, lds + 2 * 64 * 72, s_sid, blockIdx.x - 128, q, X, Brep1, rowSid1, P8_1, nullptr);
  }
}

// ---------- per-cluster epilogue: conc, logsumexp, cluster loss ----------
template<int K>
__global__ __launch_bounds__(256) void k_finalize(const float* __restrict__ P8,
    const float* __restrict__ sn2, const int* __restrict__ rowSid,
    const int* __restrict__ counts, const int* __restrict__ offsets,
    double* __restrict__ clLoss) {
  __shared__ float pcc[4096];
  __shared__ double red[256];
  __shared__ double s_conc;
  __shared__ float s_rn20;
  const int c = blockIdx.x;
  const int n = counts[c], base = offsets[c];
  const int tid = threadIdx.x;
  if (n <= 1) { if (tid == 0) clLoss[c] = 0.0; return; }

  if (tid == 0) {
    float s = 0.f;
    for (int q = 0; q < 8; q++) s += sn2[rowSid[(size_t)base * 8 + q]];
    s_rn20 = s;
  }
  __syncthreads();

  // phase 1: P[r][c] and conc
  double t = 0.0;
  for (int r = tid; r < n; r += 256) {
    float s = 0.f;
    for (int q = 0; q < 8; q++) s += P8[((size_t)q * CCH + base + r) * K + c];
    pcc[r] = s;
    float rn = 0.f;
    for (int q = 0; q < 8; q++) rn += sn2[rowSid[(size_t)(base + r) * 8 + q]];
    float d2 = rn - 2.f * s + s_rn20;
    t += sqrt((double)(d2 > 0.f ? d2 : 0.f));
  }
  red[tid] = t; __syncthreads();
  for (int o = 128; o; o >>= 1) { if (tid < o) red[tid] += red[tid + o]; __syncthreads(); }
  if (tid == 0) s_conc = red[0] / ((double)n * log((double)n + 10.0));
  __syncthreads();
  const float invc = (float)(1.0 / s_conc);

  // phase 2: per-row logsumexp over K logits
  const int wave = tid >> 6, lane = tid & 63;
  constexpr int RPW = 64 / K;
  const int sub = lane / K;
  const int cc = lane % K;
  double acc = 0.0;
  for (int r0 = wave * RPW; r0 < n; r0 += 4 * RPW) {
    int r = r0 + sub;
    bool valid = (r < n);
    float lg = -3.0e38f;
    if (valid) {
      float s = 0.f;
      for (int q = 0; q < 8; q++) s += P8[((size_t)q * CCH + base + r) * K + cc];
      lg = s * invc;
    }
    float m = lg;
    #pragma unroll
    for (int o = K / 2; o; o >>= 1) m = fmaxf(m, __shfl_xor(m, o, K));
    float e = valid ? expf(lg - m) : 0.f;
    float se = e;
    #pragma unroll
    for (int o = K / 2; o; o >>= 1) se += __shfl_xor(se, o, K);
    if (valid && cc == 0) {
      float den = m + logf(se);
      acc += (double)den - (double)(pcc[r] * invc);
    }
  }
  red[tid] = acc; __syncthreads();
  for (int o = 128; o; o >>= 1) { if (tid < o) red[tid] += red[tid + o]; __syncthreads(); }
  if (tid == 0) clLoss[c] = red[0] / (double)n;
}

// ---------- final scalars ----------
__global__ void k_final(const double* __restrict__ cl0, const double* __restrict__ cl1,
                        float* __restrict__ out) {
  if (threadIdx.x == 0) {
    double s0 = 0.0, s1 = 0.0;
    for (int i = 0; i < 64; i++) s0 += cl0[i];
    for (int i = 0; i < 16; i++) s1 += cl1[i];
    out[0] = (float)(s0 / 4096.0);
    out[1] = (float)(s1 / (2.0 * 4096.0));
  }
}

extern "C" void kernel_launch(void* const* d_in, const int* in_sizes, int n_in,
                              void* d_out, int out_size, void* d_ws, size_t ws_size,
                              hipStream_t stream) {
  const float* X = (const float*)d_in[0];
  const int* im0 = (const int*)d_in[1];
  const int* im1 = (const int*)d_in[2];
  float* out = (float*)d_out;

  char* w = (char*)d_ws;
  auto alloc = [&](size_t bytes) -> char* {
    char* p = w; w += (bytes + 255) & ~(size_t)255; return p;
  };
  int*            cnt0  = (int*)alloc(64 * 4);
  int*            off0  = (int*)alloc(64 * 4);
  int*            cnt1  = (int*)alloc(16 * 4);
  int*            off1  = (int*)alloc(16 * 4);
  int*            mem0  = (int*)alloc(CCH * 4);
  int*            mem1  = (int*)alloc(CCH * 4);
  int*            rs0   = (int*)alloc((size_t)CCH * 8 * 4);
  int*            rs1   = (int*)alloc((size_t)CCH * 8 * 4);
  float*          sn2   = (float*)alloc((size_t)8 * CCH * 4);
  unsigned short* Brep0 = (unsigned short*)alloc((size_t)8 * 64 * SPAD * 2);
  unsigned short* Brep1 = (unsigned short*)alloc((size_t)8 * 16 * SPAD * 2);
  float*          P8_0  = (float*)alloc((size_t)8 * CCH * 64 * 4);
  float*          P8_1  = (float*)alloc((size_t)8 * CCH * 16 * 4);
  double*         cl0   = (double*)alloc(64 * 8);
  double*         cl1   = (double*)alloc(16 * 8);

  hipMemsetAsync(cnt0, 0, 64 * 4, stream);
  hipMemsetAsync(cnt1, 0, 16 * 4, stream);

  k_hist<<<CCH / 256, 256, 0, stream>>>(im0, cnt0);
  k_hist<<<CCH / 256, 256, 0, stream>>>(im1, cnt1);
  k_prefix<<<1, 64, 0, stream>>>(cnt0, off0, 64);
  k_prefix<<<1, 64, 0, stream>>>(cnt1, off1, 16);
  k_members<<<64, 64, 0, stream>>>(im0, off0, mem0);
  k_members<<<16, 64, 0, stream>>>(im1, off1, mem1);
  k_rowsid<<<64, 256, 0, stream>>>(cnt0, off0, mem0, rs0);
  k_rowsid<<<16, 256, 0, stream>>>(cnt1, off1, mem1, rs1);
  k_brep<<<896, 256, 0, stream>>>(X, cnt0, off0, mem0, (unsigned int*)Brep0, 64);
  k_brep<<<224, 256, 0, stream>>>(X, cnt1, off1, mem1, (unsigned int*)Brep1, 16);
  k_gemm_fused<<<dim3(192, 8), 256, 0, stream>>>(X, Brep0, Brep1, rs0, rs1, P8_0, P8_1, sn2);
  k_finalize<64><<<64, 256, 0, stream>>>(P8_0, sn2, rs0, cnt0, off0, cl0);
  k_finalize<16><<<16, 256, 0, stream>>>(P8_1, sn2, rs1, cnt1, off1, cl1);
  k_final<<<1, 64, 0, stream>>>(cl0, cl1, out);
}

// Round 3
// 132.330 us; speedup vs baseline: 2.4833x; 1.5059x over previous
//
#include <hip/hip_runtime.h>
#include <math.h>

#define CCH 4096
#define SP 891

typedef __attribute__((ext_vector_type(8))) short short8;
typedef __attribute__((ext_vector_type(4))) float f32x4;

__device__ __forceinline__ unsigned int pack_bf2(float a, float b) {
  unsigned int ua = __builtin_bit_cast(unsigned int, a);
  unsigned int ub = __builtin_bit_cast(unsigned int, b);
  ua = (ua + 0x7fffu + ((ua >> 16) & 1u)) >> 16;
  ub = (ub + 0x7fffu + ((ub >> 16) & 1u)) >> 16;
  return ua | (ub << 16);
}

// ---------- setup 1: histograms + prefix for both levels (1 block) ----------
__global__ void k_setup1(const int* __restrict__ im0, const int* __restrict__ im1,
                         int* cnt0, int* off0, int* cnt1, int* off1) {
  __shared__ int h0[64], h1[16];
  int tid = threadIdx.x;
  if (tid < 64) h0[tid] = 0;
  if (tid < 16) h1[tid] = 0;
  __syncthreads();
  for (int ch = tid; ch < CCH; ch += 256) {
    atomicAdd(&h0[im0[ch]], 1);
    atomicAdd(&h1[im1[ch]], 1);
  }
  __syncthreads();
  if (tid == 0) {
    int s = 0;
    for (int c = 0; c < 64; c++) { off0[c] = s; cnt0[c] = h0[c]; s += h0[c]; }
    s = 0;
    for (int c = 0; c < 16; c++) { off1[c] = s; cnt1[c] = h1[c]; s += h1[c]; }
  }
}

// ---------- setup 2: members + rowSid + rowC for both levels (80 blocks x 64) ----------
__global__ void k_setup2(const int* __restrict__ im0, const int* __restrict__ im1,
                         const int* __restrict__ cnt0, const int* __restrict__ off0,
                         const int* __restrict__ cnt1, const int* __restrict__ off1,
                         int* mem, int* rs0, int* rs1, int* rowC0, int* rowC1) {
  int cb = blockIdx.x;
  int level = (cb >= 64) ? 1 : 0;
  int c = level ? cb - 64 : cb;
  const int* im = level ? im1 : im0;
  int base = level ? off1[c] : off0[c];
  int n = level ? cnt1[c] : cnt0[c];
  int* members = mem + (level ? CCH : 0);
  int* rs = level ? rs1 : rs0;
  int* rowC = level ? rowC1 : rowC0;
  int lane = threadIdx.x;
  int cnt = 0;
  for (int chunk = 0; chunk < CCH; chunk += 64) {
    int ch = chunk + lane;
    bool m = (im[ch] == c);
    unsigned long long mk = __ballot(m);
    int pos = __popcll(mk & ((1ull << lane) - 1ull));
    if (m) members[base + cnt + pos] = ch;
    cnt += __popcll(mk);
  }
  __syncthreads();
  for (int r = lane; r < n; r += 64) {
    rowC[base + r] = c;
    for (int q = 0; q < 8; q++) {
      int p = 8 * r + q;
      int b = p / n, j = p - b * n;
      rs[(size_t)(base + r) * 8 + q] = b * CCH + members[base + j];
    }
  }
}

// ---------- MFMA GEMM (one level per kernel; B staged straight from X) ----------
template<int TM, int N, bool SN2>
__global__ __launch_bounds__(256) void k_gemm(const float* __restrict__ X,
    const int* __restrict__ rowSid, const int* __restrict__ offsets,
    float* __restrict__ P8, float* __restrict__ sn2) {
  constexpr int KC = 64, LDAB = 72;
  constexpr int NCS = N / 16;          // col strips
  constexpr int WM = 4 / NCS;          // waves along M
  constexpr int FM = TM / (16 * WM);   // M frags per wave
  constexpr int AI = TM * 16 / 256;    // A float4-chunks per thread
  constexpr int BI = N * 16 / 256;     // B float4-chunks per thread
  constexpr int NSTEP = (SP + KC - 1) / KC; // 14
  __shared__ short As[2 * TM * LDAB];
  __shared__ short Bs[2 * N * LDAB];
  __shared__ int sidA[TM];
  __shared__ int sidB[N];
  const int q = blockIdx.y, row0 = blockIdx.x * TM, tid = threadIdx.x;
  if (tid < TM) sidA[tid] = rowSid[(size_t)(row0 + tid) * 8 + q];
  if (tid >= 64 && tid < 64 + N) sidB[tid - 64] = rowSid[(size_t)offsets[tid - 64] * 8 + q];
  __syncthreads();
  const int l = tid & 63, w = tid >> 6;
  const int cbase = (w % NCS) * 16;
  const int mbase = (w / NCS) * (FM * 16);
  const int lrow = l & 15;
  const int lk = (l >> 4) * 8;

  const float* aptr[AI];
  const float* bptr[BI];
  #pragma unroll
  for (int i = 0; i < AI; i++) {
    int idx = i * 256 + tid;
    aptr[i] = X + (size_t)sidA[idx >> 4] * SP + (idx & 15) * 4;
  }
  #pragma unroll
  for (int i = 0; i < BI; i++) {
    int idx = i * 256 + tid;
    bptr[i] = X + (size_t)sidB[idx >> 4] * SP + (idx & 15) * 4;
  }
  f32x4 acc[FM];
  #pragma unroll
  for (int m = 0; m < FM; m++) acc[m] = (f32x4){0.f, 0.f, 0.f, 0.f};
  float acc2[AI];
  #pragma unroll
  for (int i = 0; i < AI; i++) acc2[i] = 0.f;
  float4 arg[AI], brg[BI];

  auto LOADG = [&](int t) {
    const int k0 = t * KC;
    if (k0 + KC <= SP) {
      #pragma unroll
      for (int i = 0; i < AI; i++) { const float* p = aptr[i] + k0; arg[i] = make_float4(p[0], p[1], p[2], p[3]); }
      #pragma unroll
      for (int i = 0; i < BI; i++) { const float* p = bptr[i] + k0; brg[i] = make_float4(p[0], p[1], p[2], p[3]); }
    } else {
      #pragma unroll
      for (int i = 0; i < AI; i++) {
        int kb = k0 + ((i * 256 + tid) & 15) * 4;
        const float* p = aptr[i] + k0;
        arg[i].x = (kb < SP) ? p[0] : 0.f;
        arg[i].y = (kb + 1 < SP) ? p[1] : 0.f;
        arg[i].z = (kb + 2 < SP) ? p[2] : 0.f;
        arg[i].w = (kb + 3 < SP) ? p[3] : 0.f;
      }
      #pragma unroll
      for (int i = 0; i < BI; i++) {
        int kb = k0 + ((i * 256 + tid) & 15) * 4;
        const float* p = bptr[i] + k0;
        brg[i].x = (kb < SP) ? p[0] : 0.f;
        brg[i].y = (kb + 1 < SP) ? p[1] : 0.f;
        brg[i].z = (kb + 2 < SP) ? p[2] : 0.f;
        brg[i].w = (kb + 3 < SP) ? p[3] : 0.f;
      }
    }
  };
  auto STORE = [&](int buf) {
    #pragma unroll
    for (int i = 0; i < AI; i++) {
      int idx = i * 256 + tid;
      int arow = idx >> 4, k2 = (idx & 15) * 4;
      uint2 u;
      u.x = pack_bf2(arg[i].x, arg[i].y);
      u.y = pack_bf2(arg[i].z, arg[i].w);
      *(uint2*)(&As[(buf * TM + arow) * LDAB + k2]) = u;
      if (SN2) acc2[i] += arg[i].x * arg[i].x + arg[i].y * arg[i].y + arg[i].z * arg[i].z + arg[i].w * arg[i].w;
    }
    #pragma unroll
    for (int i = 0; i < BI; i++) {
      int idx = i * 256 + tid;
      int brow = idx >> 4, k2 = (idx & 15) * 4;
      uint2 u;
      u.x = pack_bf2(brg[i].x, brg[i].y);
      u.y = pack_bf2(brg[i].z, brg[i].w);
      *(uint2*)(&Bs[(buf * N + brow) * LDAB + k2]) = u;
    }
  };

  LOADG(0); STORE(0); __syncthreads();
  for (int t = 0; t < NSTEP; t++) {
    int buf = t & 1;
    if (t + 1 < NSTEP) LOADG(t + 1);
    #pragma unroll
    for (int kk = 0; kk < 2; kk++) {
      short8 bfr = *(const short8*)(&Bs[(buf * N + cbase + lrow) * LDAB + lk + kk * 32]);
      #pragma unroll
      for (int m = 0; m < FM; m++) {
        short8 afr = *(const short8*)(&As[(buf * TM + mbase + m * 16 + lrow) * LDAB + lk + kk * 32]);
        acc[m] = __builtin_amdgcn_mfma_f32_16x16x32_bf16(afr, bfr, acc[m], 0, 0, 0);
      }
    }
    if (t + 1 < NSTEP) { __syncthreads(); STORE(buf ^ 1); __syncthreads(); }
  }
  #pragma unroll
  for (int m = 0; m < FM; m++) {
    #pragma unroll
    for (int r = 0; r < 4; r++) {
      int row = row0 + mbase + m * 16 + (l >> 4) * 4 + r;
      P8[((size_t)q * CCH + row) * N + cbase + lrow] = acc[m][r];
    }
  }
  if (SN2) {
    #pragma unroll
    for (int i = 0; i < AI; i++) {
      float s = acc2[i];
      s += __shfl_xor(s, 1, 16); s += __shfl_xor(s, 2, 16);
      s += __shfl_xor(s, 4, 16); s += __shfl_xor(s, 8, 16);
      if ((tid & 15) == 0) sn2[sidA[(i * 256 + tid) >> 4]] = s;
    }
  }
}

// ---------- fin1: conc numerators (row-parallel, both levels, 256 blocks) ----------
__global__ __launch_bounds__(256) void k_fin1(const float* __restrict__ P8_0,
    const float* __restrict__ P8_1, const float* __restrict__ sn2,
    const int* __restrict__ rs0, const int* __restrict__ rs1,
    const int* __restrict__ off0, const int* __restrict__ off1,
    const int* __restrict__ rowC0, const int* __restrict__ rowC1,
    float* __restrict__ concNum) {
  __shared__ float cl[80];
  int tid = threadIdx.x;
  if (tid < 80) cl[tid] = 0.f;
  __syncthreads();
  int level = blockIdx.x >> 7;
  int rbase = (blockIdx.x & 127) * 32;
  const float* P8 = level ? P8_1 : P8_0;
  const int* rs = level ? rs1 : rs0;
  const int* off = level ? off1 : off0;
  const int* rowC = level ? rowC1 : rowC0;
  int K = level ? 16 : 64;
  int row = rbase + (tid >> 3), q = tid & 7;
  int c = rowC[row];
  float p = P8[((size_t)q * CCH + row) * K + c];
  float rn = sn2[rs[(size_t)row * 8 + q]];
  for (int o = 1; o < 8; o <<= 1) { p += __shfl_xor(p, o, 8); rn += __shfl_xor(rn, o, 8); }
  if (q == 0) {
    int base = off[c];
    if (row != base) {  // row 0 of a cluster contributes exactly 0 (matches ref)
      float rn0 = 0.f;
      for (int qq = 0; qq < 8; qq++) rn0 += sn2[rs[(size_t)base * 8 + qq]];
      float d2 = rn - 2.f * p + rn0;
      float sv = (d2 > 0.f) ? sqrtf(d2) : 0.f;
      atomicAdd(&cl[level * 64 + c], sv);
    }
  }
  __syncthreads();
  if (tid < 80 && cl[tid] != 0.f) atomicAdd(&concNum[tid], cl[tid]);
}

// ---------- fin2: per-row logsumexp + loss accumulation ----------
template<int K>
__global__ __launch_bounds__(256) void k_fin2(const float* __restrict__ P8,
    const int* __restrict__ counts, const int* __restrict__ rowC,
    const float* __restrict__ concNum, int cbase_g,
    float* __restrict__ lossAcc, int lidx) {
  __shared__ float lsum;
  if (threadIdx.x == 0) lsum = 0.f;
  __syncthreads();
  constexpr int RPW = 64 / K;
  int w = threadIdx.x >> 6, lane = threadIdx.x & 63;
  int sub = (K == 64) ? 0 : (lane >> 4);
  int row = blockIdx.x * (4 * RPW) + w * RPW + sub;
  int cc = lane & (K - 1);
  int c = rowC[row];
  int n = counts[c];
  float conc = concNum[cbase_g + c] / ((float)n * logf((float)n + 10.f));
  float invc = 1.f / conc;
  float s = 0.f;
  #pragma unroll
  for (int q = 0; q < 8; q++) s += P8[((size_t)q * CCH + row) * K + cc];
  float lg = s * invc;
  float nomv = __shfl(lg, (lane & ~(K - 1)) + c, 64);
  float m = lg;
  #pragma unroll
  for (int o = K / 2; o; o >>= 1) m = fmaxf(m, __shfl_xor(m, o, K));
  float e = expf(lg - m);
  float se = e;
  #pragma unroll
  for (int o = K / 2; o; o >>= 1) se += __shfl_xor(se, o, K);
  if (cc == 0 && n >= 2) {
    float contrib = (m + logf(se) - nomv) / (float)n;
    atomicAdd(&lsum, contrib);
  }
  __syncthreads();
  if (threadIdx.x == 0) atomicAdd(&lossAcc[lidx], lsum);
}

// ---------- final scalars ----------
__global__ void k_final(const float* __restrict__ lossAcc, float* __restrict__ out) {
  if (threadIdx.x == 0) {
    out[0] = lossAcc[0] / 4096.0f;
    out[1] = lossAcc[1] / 8192.0f;
  }
}

extern "C" void kernel_launch(void* const* d_in, const int* in_sizes, int n_in,
                              void* d_out, int out_size, void* d_ws, size_t ws_size,
                              hipStream_t stream) {
  const float* X = (const float*)d_in[0];
  const int* im0 = (const int*)d_in[1];
  const int* im1 = (const int*)d_in[2];
  float* out = (float*)d_out;

  char* w = (char*)d_ws;
  auto alloc = [&](size_t bytes) -> char* {
    char* p = w; w += (bytes + 255) & ~(size_t)255; return p;
  };
  float* concNum = (float*)alloc((80 + 2) * 4);  // concNum[80] + lossAcc[2], one memset
  float* lossAcc = concNum + 80;
  int*   cnt0  = (int*)alloc(64 * 4);
  int*   off0  = (int*)alloc(64 * 4);
  int*   cnt1  = (int*)alloc(16 * 4);
  int*   off1  = (int*)alloc(16 * 4);
  int*   mem   = (int*)alloc((size_t)2 * CCH * 4);
  int*   rs0   = (int*)alloc((size_t)CCH * 8 * 4);
  int*   rs1   = (int*)alloc((size_t)CCH * 8 * 4);
  int*   rowC0 = (int*)alloc((size_t)CCH * 4);
  int*   rowC1 = (int*)alloc((size_t)CCH * 4);
  float* sn2   = (float*)alloc((size_t)8 * CCH * 4);
  float* P8_0  = (float*)alloc((size_t)8 * CCH * 64 * 4);
  float* P8_1  = (float*)alloc((size_t)8 * CCH * 16 * 4);

  hipMemsetAsync(concNum, 0, (80 + 2) * 4, stream);
  k_setup1<<<1, 256, 0, stream>>>(im0, im1, cnt0, off0, cnt1, off1);
  k_setup2<<<80, 64, 0, stream>>>(im0, im1, cnt0, off0, cnt1, off1, mem, rs0, rs1, rowC0, rowC1);
  k_gemm<32, 64, true><<<dim3(CCH / 32, 8), 256, 0, stream>>>(X, rs0, off0, P8_0, sn2);
  k_gemm<64, 16, false><<<dim3(CCH / 64, 8), 256, 0, stream>>>(X, rs1, off1, P8_1, nullptr);
  k_fin1<<<256, 256, 0, stream>>>(P8_0, P8_1, sn2, rs0, rs1, off0, off1, rowC0, rowC1, concNum);
  k_fin2<64><<<CCH / 4, 256, 0, stream>>>(P8_0, cnt0, rowC0, concNum, 0, lossAcc, 0);
  k_fin2<16><<<CCH / 16, 256, 0, stream>>>(P8_1, cnt1, rowC1, concNum, 64, lossAcc, 1);
  k_final<<<1, 64, 0, stream>>>(lossAcc, out);
}

// Round 4
// 127.207 us; speedup vs baseline: 2.5833x; 1.0403x over previous
//
#include <hip/hip_runtime.h>
#include <math.h>

#define CCH 4096
#define SP 891
#define NSL 32768          // 8*4096 slices
#define SPADE 896          // padded slice length (bf16 elems)

typedef __attribute__((ext_vector_type(8))) short short8;
typedef __attribute__((ext_vector_type(4))) float f32x4;

__device__ __forceinline__ unsigned int pack_bf2(float a, float b) {
  unsigned int ua = __builtin_bit_cast(unsigned int, a);
  unsigned int ub = __builtin_bit_cast(unsigned int, b);
  ua = (ua + 0x7fffu + ((ua >> 16) & 1u)) >> 16;
  ub = (ub + 0x7fffu + ((ub >> 16) & 1u)) >> 16;
  return ua | (ub << 16);
}

__device__ __forceinline__ void gload_lds16(const void* g, void* l) {
  __builtin_amdgcn_global_load_lds(
      (const __attribute__((address_space(1))) unsigned int*)g,
      (__attribute__((address_space(3))) unsigned int*)l, 16, 0, 0);
}

// ---------- setup 1: histograms + prefix for both levels (1 block) ----------
__global__ void k_setup1(const int* __restrict__ im0, const int* __restrict__ im1,
                         int* cnt0, int* off0, int* cnt1, int* off1) {
  __shared__ int h0[64], h1[16];
  int tid = threadIdx.x;
  if (tid < 64) h0[tid] = 0;
  if (tid < 16) h1[tid] = 0;
  __syncthreads();
  for (int ch = tid; ch < CCH; ch += 256) {
    atomicAdd(&h0[im0[ch]], 1);
    atomicAdd(&h1[im1[ch]], 1);
  }
  __syncthreads();
  if (tid == 0) {
    int s = 0;
    for (int c = 0; c < 64; c++) { off0[c] = s; cnt0[c] = h0[c]; s += h0[c]; }
    s = 0;
    for (int c = 0; c < 16; c++) { off1[c] = s; cnt1[c] = h1[c]; s += h1[c]; }
  }
}

// ---------- setup 2: members + rowSid + rowC (80 blocks x 64) ----------
__global__ void k_setup2(const int* __restrict__ im0, const int* __restrict__ im1,
                         const int* __restrict__ cnt0, const int* __restrict__ off0,
                         const int* __restrict__ cnt1, const int* __restrict__ off1,
                         int* mem, int* rs0, int* rs1, int* rowC0, int* rowC1) {
  int cb = blockIdx.x;
  int level = (cb >= 64) ? 1 : 0;
  int c = level ? cb - 64 : cb;
  const int* im = level ? im1 : im0;
  int base = level ? off1[c] : off0[c];
  int n = level ? cnt1[c] : cnt0[c];
  int* members = mem + (level ? CCH : 0);
  int* rs = level ? rs1 : rs0;
  int* rowC = level ? rowC1 : rowC0;
  int lane = threadIdx.x;
  int cnt = 0;
  for (int chunk = 0; chunk < CCH; chunk += 64) {
    int ch = chunk + lane;
    bool m = (im[ch] == c);
    unsigned long long mk = __ballot(m);
    int pos = __popcll(mk & ((1ull << lane) - 1ull));
    if (m) members[base + cnt + pos] = ch;
    cnt += __popcll(mk);
  }
  __syncthreads();
  for (int r = lane; r < n; r += 64) {
    rowC[base + r] = c;
    for (int q = 0; q < 8; q++) {
      int p = 8 * r + q;
      int b = p / n, j = p - b * n;
      rs[(size_t)(base + r) * 8 + q] = b * CCH + members[base + j];
    }
  }
}

// ---------- convert X -> bf16 (padded), fused slice-norms ----------
__global__ __launch_bounds__(256) void k_convert(const float* __restrict__ X,
    unsigned int* __restrict__ Xbf32, float* __restrict__ sn2) {
  int w = threadIdx.x >> 6, l = threadIdx.x & 63;
  for (int sid = blockIdx.x * 4 + w; sid < NSL; sid += gridDim.x * 4) {
    const float* src = X + (size_t)sid * SP;
    unsigned int* dst = Xbf32 + (size_t)sid * (SPADE / 2);
    float s2 = 0.f;
    #pragma unroll
    for (int p = 0; p < 7; p++) {
      int e = p * 128 + l * 2;
      float v0 = (e < SP) ? src[e] : 0.f;
      float v1 = (e + 1 < SP) ? src[e + 1] : 0.f;
      s2 += v0 * v0 + v1 * v1;
      dst[p * 64 + l] = pack_bf2(v0, v1);
    }
    for (int o = 32; o; o >>= 1) s2 += __shfl_xor(s2, o, 64);
    if (l == 0) sn2[sid] = s2;
  }
}

// ---------- MFMA GEMM via global_load_lds, swizzled LDS ----------
// P8[q][row][c'] = dot(Xbf[sidA(row,q)], Xbf[sidB(c',q)])
template<int TM, int N, int WM>
__global__ __launch_bounds__(256) void k_gemm(const unsigned short* __restrict__ Xbf,
    const int* __restrict__ rowSid, const int* __restrict__ offsets,
    float* __restrict__ P8) {
  constexpr int NSTEP = SPADE / 64;       // 14
  constexpr int WN = 4 / WM;
  constexpr int NS = N / (16 * WN);       // col strips per wave
  constexpr int AI = TM / 32;             // A gload insts per wave
  constexpr int BTOT = N / 8;             // total B gload insts
  constexpr int BI = (BTOT + 3) / 4;      // per-wave B insts (max)
  __shared__ __align__(16) unsigned short As[2 * TM * 64];
  __shared__ __align__(16) unsigned short Bs[2 * N * 64];
  __shared__ int sidA[TM];
  __shared__ int sidB[N];
  const int q = blockIdx.y, row0 = blockIdx.x * TM, tid = threadIdx.x;
  if (tid < TM) sidA[tid] = rowSid[(size_t)(row0 + tid) * 8 + q];
  if (tid >= 128 && tid < 128 + N) sidB[tid - 128] = rowSid[(size_t)offsets[tid - 128] * 8 + q];
  __syncthreads();
  const int l = tid & 63, w = tid >> 6;
  const int wm = w % WM, wn = w / WM;
  const int mbase = wm * 16;
  const int lrow = l & 15;
  // per-lane global sources, pre-swizzled: LDS[r][c] <- G[r][c ^ (r&7)]
  const int gl_r = l >> 3;                // row within 8-row group
  const int swz_g = (l & 7) ^ gl_r;       // (r&7) == gl_r for aligned groups
  const char* gA[AI];
  #pragma unroll
  for (int i = 0; i < AI; i++) {
    int ia = w * AI + i;
    gA[i] = (const char*)Xbf + (size_t)sidA[ia * 8 + gl_r] * (SPADE * 2) + swz_g * 16;
  }
  const char* gB[BI];
  #pragma unroll
  for (int i = 0; i < BI; i++) {
    int ib = w + i * 4;
    gB[i] = (ib < BTOT)
        ? ((const char*)Xbf + (size_t)sidB[ib * 8 + gl_r] * (SPADE * 2) + swz_g * 16)
        : (const char*)Xbf;
  }

  f32x4 acc[NS];
  #pragma unroll
  for (int s = 0; s < NS; s++) acc[s] = (f32x4){0.f, 0.f, 0.f, 0.f};

  auto STAGE = [&](int t, int buf) {
    #pragma unroll
    for (int i = 0; i < AI; i++) {
      int ia = w * AI + i;
      gload_lds16(gA[i] + t * 128, (char*)As + (size_t)(buf * TM + ia * 8) * 128);
    }
    #pragma unroll
    for (int i = 0; i < BI; i++) {
      if (w + i * 4 < BTOT)
        gload_lds16(gB[i] + t * 128, (char*)Bs + (size_t)(buf * N + (w + i * 4) * 8) * 128);
    }
  };

  STAGE(0, 0);
  __syncthreads();
  #pragma unroll
  for (int t = 0; t < NSTEP; t++) {
    const int buf = t & 1;
    if (t + 1 < NSTEP) STAGE(t + 1, buf ^ 1);
    #pragma unroll
    for (int kk = 0; kk < 2; kk++) {
      const int ca = kk * 4 + (l >> 4);
      const int sw = (ca ^ (lrow & 7)) * 16;
      short8 afr = *(const short8*)((const char*)As + (size_t)(buf * TM + mbase + lrow) * 128 + sw);
      #pragma unroll
      for (int s = 0; s < NS; s++) {
        int brow = (wn * NS + s) * 16 + lrow;
        short8 bfr = *(const short8*)((const char*)Bs + (size_t)(buf * N + brow) * 128 + sw);
        acc[s] = __builtin_amdgcn_mfma_f32_16x16x32_bf16(afr, bfr, acc[s], 0, 0, 0);
      }
    }
    if (t + 1 < NSTEP) __syncthreads();
  }
  #pragma unroll
  for (int s = 0; s < NS; s++) {
    #pragma unroll
    for (int r = 0; r < 4; r++) {
      int row = row0 + mbase + (l >> 4) * 4 + r;
      int col = (wn * NS + s) * 16 + lrow;
      P8[((size_t)q * CCH + row) * N + col] = acc[s][r];
    }
  }
}

// ---------- fin1: conc numerators (row-parallel, both levels) ----------
__global__ __launch_bounds__(256) void k_fin1(const float* __restrict__ P8_0,
    const float* __restrict__ P8_1, const float* __restrict__ sn2,
    const int* __restrict__ rs0, const int* __restrict__ rs1,
    const int* __restrict__ off0, const int* __restrict__ off1,
    const int* __restrict__ rowC0, const int* __restrict__ rowC1,
    float* __restrict__ concNum) {
  __shared__ float cl[80];
  int tid = threadIdx.x;
  if (tid < 80) cl[tid] = 0.f;
  __syncthreads();
  int level = blockIdx.x >> 7;
  int rbase = (blockIdx.x & 127) * 32;
  const float* P8 = level ? P8_1 : P8_0;
  const int* rs = level ? rs1 : rs0;
  const int* off = level ? off1 : off0;
  const int* rowC = level ? rowC1 : rowC0;
  int K = level ? 16 : 64;
  int row = rbase + (tid >> 3), q = tid & 7;
  int c = rowC[row];
  float p = P8[((size_t)q * CCH + row) * K + c];
  float rn = sn2[rs[(size_t)row * 8 + q]];
  for (int o = 1; o < 8; o <<= 1) { p += __shfl_xor(p, o, 8); rn += __shfl_xor(rn, o, 8); }
  if (q == 0) {
    int base = off[c];
    if (row != base) {
      float rn0 = 0.f;
      for (int qq = 0; qq < 8; qq++) rn0 += sn2[rs[(size_t)base * 8 + qq]];
      float d2 = rn - 2.f * p + rn0;
      float sv = (d2 > 0.f) ? sqrtf(d2) : 0.f;
      atomicAdd(&cl[level * 64 + c], sv);
    }
  }
  __syncthreads();
  if (tid < 80 && cl[tid] != 0.f) atomicAdd(&concNum[tid], cl[tid]);
}

// ---------- fin2: per-row logsumexp + loss ----------
template<int K>
__global__ __launch_bounds__(256) void k_fin2(const float* __restrict__ P8,
    const int* __restrict__ counts, const int* __restrict__ rowC,
    const float* __restrict__ concNum, int cbase_g,
    float* __restrict__ lossAcc, int lidx) {
  __shared__ float lsum;
  if (threadIdx.x == 0) lsum = 0.f;
  __syncthreads();
  constexpr int RPW = 64 / K;
  int w = threadIdx.x >> 6, lane = threadIdx.x & 63;
  int sub = (K == 64) ? 0 : (lane >> 4);
  int row = blockIdx.x * (4 * RPW) + w * RPW + sub;
  int cc = lane & (K - 1);
  int c = rowC[row];
  int n = counts[c];
  float conc = concNum[cbase_g + c] / ((float)n * logf((float)n + 10.f));
  float invc = 1.f / conc;
  float s = 0.f;
  #pragma unroll
  for (int q = 0; q < 8; q++) s += P8[((size_t)q * CCH + row) * K + cc];
  float lg = s * invc;
  float nomv = __shfl(lg, (lane & ~(K - 1)) + c, 64);
  float m = lg;
  #pragma unroll
  for (int o = K / 2; o; o >>= 1) m = fmaxf(m, __shfl_xor(m, o, K));
  float e = expf(lg - m);
  float se = e;
  #pragma unroll
  for (int o = K / 2; o; o >>= 1) se += __shfl_xor(se, o, K);
  if (cc == 0 && n >= 2) {
    float contrib = (m + logf(se) - nomv) / (float)n;
    atomicAdd(&lsum, contrib);
  }
  __syncthreads();
  if (threadIdx.x == 0) atomicAdd(&lossAcc[lidx], lsum);
}

// ---------- final scalars ----------
__global__ void k_final(const float* __restrict__ lossAcc, float* __restrict__ out) {
  if (threadIdx.x == 0) {
    out[0] = lossAcc[0] / 4096.0f;
    out[1] = lossAcc[1] / 8192.0f;
  }
}

extern "C" void kernel_launch(void* const* d_in, const int* in_sizes, int n_in,
                              void* d_out, int out_size, void* d_ws, size_t ws_size,
                              hipStream_t stream) {
  const float* X = (const float*)d_in[0];
  const int* im0 = (const int*)d_in[1];
  const int* im1 = (const int*)d_in[2];
  float* out = (float*)d_out;

  char* w = (char*)d_ws;
  auto alloc = [&](size_t bytes) -> char* {
    char* p = w; w += (bytes + 255) & ~(size_t)255; return p;
  };
  float* concNum = (float*)alloc((80 + 2) * 4);
  float* lossAcc = concNum + 80;
  int*   cnt0  = (int*)alloc(64 * 4);
  int*   off0  = (int*)alloc(64 * 4);
  int*   cnt1  = (int*)alloc(16 * 4);
  int*   off1  = (int*)alloc(16 * 4);
  int*   mem   = (int*)alloc((size_t)2 * CCH * 4);
  int*   rs0   = (int*)alloc((size_t)CCH * 8 * 4);
  int*   rs1   = (int*)alloc((size_t)CCH * 8 * 4);
  int*   rowC0 = (int*)alloc((size_t)CCH * 4);
  int*   rowC1 = (int*)alloc((size_t)CCH * 4);
  float* sn2   = (float*)alloc((size_t)NSL * 4);
  unsigned short* Xbf = (unsigned short*)alloc((size_t)NSL * SPADE * 2);
  float* P8_0  = (float*)alloc((size_t)8 * CCH * 64 * 4);
  float* P8_1  = (float*)alloc((size_t)8 * CCH * 16 * 4);

  hipMemsetAsync(concNum, 0, (80 + 2) * 4, stream);
  k_setup1<<<1, 256, 0, stream>>>(im0, im1, cnt0, off0, cnt1, off1);
  k_setup2<<<80, 64, 0, stream>>>(im0, im1, cnt0, off0, cnt1, off1, mem, rs0, rs1, rowC0, rowC1);
  k_convert<<<2048, 256, 0, stream>>>(X, (unsigned int*)Xbf, sn2);
  k_gemm<32, 64, 2><<<dim3(CCH / 32, 8), 256, 0, stream>>>(Xbf, rs0, off0, P8_0);
  k_gemm<64, 16, 4><<<dim3(CCH / 64, 8), 256, 0, stream>>>(Xbf, rs1, off1, P8_1);
  k_fin1<<<256, 256, 0, stream>>>(P8_0, P8_1, sn2, rs0, rs1, off0, off1, rowC0, rowC1, concNum);
  k_fin2<64><<<CCH / 4, 256, 0, stream>>>(P8_0, cnt0, rowC0, concNum, 0, lossAcc, 0);
  k_fin2<16><<<CCH / 16, 256, 0, stream>>>(P8_1, cnt1, rowC1, concNum, 64, lossAcc, 1);
  k_final<<<1, 64, 0, stream>>>(lossAcc, out);
}

// Round 5
// 124.844 us; speedup vs baseline: 2.6322x; 1.0189x over previous
//
#include <hip/hip_runtime.h>
#include <math.h>

#define CCH 4096
#define SP 891
#define SPADE 896

typedef __attribute__((ext_vector_type(8))) short short8;
typedef __attribute__((ext_vector_type(4))) float f32x4;

__device__ __forceinline__ unsigned int pack_bf2(float a, float b) {
  unsigned int ua = __builtin_bit_cast(unsigned int, a);
  unsigned int ub = __builtin_bit_cast(unsigned int, b);
  ua = (ua + 0x7fffu + ((ua >> 16) & 1u)) >> 16;
  ub = (ub + 0x7fffu + ((ub >> 16) & 1u)) >> 16;
  return ua | (ub << 16);
}

__device__ __forceinline__ void gload_lds16(const void* g, void* l) {
  __builtin_amdgcn_global_load_lds(
      (const __attribute__((address_space(1))) unsigned int*)g,
      (__attribute__((address_space(3))) unsigned int*)l, 16, 0, 0);
}

// ---------- setup: members + rowSid + cnt/off, self-contained (80 blocks x 64) ----------
__global__ void k_setup(const int* __restrict__ im0, const int* __restrict__ im1,
                        int* cnt0, int* off0, int* cnt1, int* off1,
                        int* mem0, int* mem1, int* rs0, int* rs1) {
  int cb = blockIdx.x;
  int level = (cb >= 64) ? 1 : 0;
  int c = level ? cb - 64 : cb;
  const int* im = level ? im1 : im0;
  int* members = level ? mem1 : mem0;
  int* rs = level ? rs1 : rs0;
  int lane = threadIdx.x;  // 64
  // pass 1: offset = #(im < c)
  int lt = 0;
  for (int ch = lane; ch < CCH; ch += 64) lt += (im[ch] < c) ? 1 : 0;
  for (int o = 32; o; o >>= 1) lt += __shfl_xor(lt, o, 64);
  int base = lt;
  // pass 2: ballot-append members (sorted)
  int cnt = 0;
  for (int chunk = 0; chunk < CCH; chunk += 64) {
    int ch = chunk + lane;
    bool m = (im[ch] == c);
    unsigned long long mk = __ballot(m);
    int pos = __popcll(mk & ((1ull << lane) - 1ull));
    if (m) members[base + cnt + pos] = ch;
    cnt += __popcll(mk);
  }
  int n = cnt;
  if (lane == 0) {
    if (level) { cnt1[c] = n; off1[c] = base; }
    else       { cnt0[c] = n; off0[c] = base; }
  }
  __syncthreads();  // drain member stores before re-reading
  for (int r = lane; r < n; r += 64) {
    #pragma unroll
    for (int q = 0; q < 8; q++) {
      int p = 8 * r + q;
      int b = p / n, j = p - b * n;
      rs[(size_t)(base + r) * 8 + q] = b * CCH + members[base + j];
    }
  }
}

// ---------- pack the 640 rep slices to bf16 (padded to 896) ----------
__global__ void k_brep(const float* __restrict__ X,
    const int* __restrict__ cnt0, const int* __restrict__ off0,
    const int* __restrict__ cnt1, const int* __restrict__ off1,
    const int* __restrict__ mem0, const int* __restrict__ mem1,
    unsigned int* __restrict__ Brep0, unsigned int* __restrict__ Brep1) {
  int idx = blockIdx.x * 4 + (threadIdx.x >> 6);  // 0..639
  int l = threadIdx.x & 63;
  int level = (idx >= 512) ? 1 : 0;
  int t = level ? idx - 512 : idx;
  int c = t >> 3, q = t & 7;
  int n = level ? cnt1[c] : cnt0[c];
  int base = level ? off1[c] : off0[c];
  const int* mem = level ? mem1 : mem0;
  int b = q / n, j = q - b * n;
  const float* src = X + (size_t)(b * CCH + mem[base + j]) * SP;
  unsigned int* dst = (level ? Brep1 : Brep0) + (size_t)t * (SPADE / 2);
  #pragma unroll
  for (int p = 0; p < 7; p++) {
    int e = p * 128 + l * 2;
    float v0 = (e < SP) ? src[e] : 0.f;
    float v1 = (e + 1 < SP) ? src[e + 1] : 0.f;
    dst[p * 64 + l] = pack_bf2(v0, v1);
  }
}

// ---------- fused MFMA GEMM: A from X fp32 (reg->pack->swz ds_write, optional sn2),
// ----------                  B from Brep via global_load_lds (pre-swizzled source)
template<int TM, int N, bool SN2>
__global__ __launch_bounds__(256) void k_gemm(const float* __restrict__ X,
    const unsigned short* __restrict__ Brep,  // [N*8][896] bf16
    const int* __restrict__ rs,
    float* __restrict__ P8, float* __restrict__ sn2) {
  constexpr int NSTEP = 14;
  constexpr int AI = (TM * 8) / 256;        // (row,chunk) pairs per thread
  constexpr int WM = (N == 64) ? 2 : 4;
  constexpr int WN = 4 / WM;
  constexpr int NS = N / (16 * WN);         // col strips per wave
  constexpr int BG = N / 8;                 // B 8-row groups
  constexpr int BPW = (BG + 3) / 4;
  __shared__ __align__(16) unsigned short As[2 * TM * 64];
  __shared__ __align__(16) unsigned short Bs[2 * N * 64];
  __shared__ int sidA[TM];
  const int q = blockIdx.y, row0 = blockIdx.x * TM, tid = threadIdx.x;
  if (tid < TM) sidA[tid] = rs[(size_t)(row0 + tid) * 8 + q];
  __syncthreads();
  const int l = tid & 63, w = tid >> 6;
  const int mbase = (w % WM) * 16;
  const int wn = w / WM;
  const int lrow = l & 15;

  // A staging geometry
  int ar[AI], ac[AI];
  const float* aSrc[AI];
  unsigned short* aLds[AI];
  #pragma unroll
  for (int i = 0; i < AI; i++) {
    int idx = i * 256 + tid;
    ar[i] = idx >> 3; ac[i] = idx & 7;
    aSrc[i] = X + (size_t)sidA[ar[i]] * SP + ac[i] * 8;
    aLds[i] = As + ar[i] * 64 + ((ac[i] ^ (ar[i] & 7)) * 8);
  }
  // B staging geometry (wave-uniform LDS dest, per-lane pre-swizzled source)
  const int gl_r = l >> 3, swz_g = (l & 7) ^ gl_r;
  const char* gBsrc[BPW];
  int bgrp[BPW];
  const bool bAct = (N == 64) || (w < BG);
  #pragma unroll
  for (int i = 0; i < BPW; i++) {
    int grp = (N == 64) ? (w * BPW + i) : w;
    bgrp[i] = grp;
    int cc = (grp < BG) ? grp * 8 + gl_r : gl_r;
    gBsrc[i] = (const char*)Brep + ((size_t)cc * 8 + q) * (SPADE * 2) + swz_g * 16;
  }

  f32x4 acc[NS];
  #pragma unroll
  for (int s = 0; s < NS; s++) acc[s] = (f32x4){0.f, 0.f, 0.f, 0.f};
  float fa[AI][8];
  float acc2[AI];
  #pragma unroll
  for (int i = 0; i < AI; i++) acc2[i] = 0.f;

  auto LOADA = [&](int t) {
    #pragma unroll
    for (int i = 0; i < AI; i++) {
      const float* p = aSrc[i] + t * 64;
      int kb = t * 64 + ac[i] * 8;
      if (kb + 8 <= SP) {
        #pragma unroll
        for (int j = 0; j < 8; j++) fa[i][j] = p[j];
      } else {
        #pragma unroll
        for (int j = 0; j < 8; j++) fa[i][j] = (kb + j < SP) ? p[j] : 0.f;
      }
    }
  };
  auto STAGEB = [&](int t, int buf) {
    if (bAct) {
      #pragma unroll
      for (int i = 0; i < BPW; i++)
        gload_lds16(gBsrc[i] + t * 128, (char*)Bs + (size_t)(buf * N + bgrp[i] * 8) * 128);
    }
  };
  auto PACKA = [&](int buf) {
    #pragma unroll
    for (int i = 0; i < AI; i++) {
      uint4 u;
      u.x = pack_bf2(fa[i][0], fa[i][1]); u.y = pack_bf2(fa[i][2], fa[i][3]);
      u.z = pack_bf2(fa[i][4], fa[i][5]); u.w = pack_bf2(fa[i][6], fa[i][7]);
      *(uint4*)(aLds[i] + (size_t)buf * TM * 64) = u;
      if (SN2) {
        #pragma unroll
        for (int j = 0; j < 8; j++) acc2[i] += fa[i][j] * fa[i][j];
      }
    }
  };

  LOADA(0); STAGEB(0, 0); PACKA(0);
  __syncthreads();
  for (int t = 0; t < NSTEP; t++) {
    const int buf = t & 1;
    const bool more = (t + 1 < NSTEP);
    if (more) { LOADA(t + 1); STAGEB(t + 1, buf ^ 1); }
    #pragma unroll
    for (int kk = 0; kk < 2; kk++) {
      const int ca = kk * 4 + (l >> 4);
      const int arow = mbase + lrow;
      short8 afr = *(const short8*)(As + (size_t)(buf * TM + arow) * 64 + ((ca ^ (arow & 7)) * 8));
      #pragma unroll
      for (int s = 0; s < NS; s++) {
        int brow = (wn * NS + s) * 16 + lrow;
        short8 bfr = *(const short8*)(Bs + (size_t)(buf * N + brow) * 64 + ((ca ^ (brow & 7)) * 8));
        acc[s] = __builtin_amdgcn_mfma_f32_16x16x32_bf16(afr, bfr, acc[s], 0, 0, 0);
      }
    }
    if (more) PACKA(buf ^ 1);
    __syncthreads();
  }
  #pragma unroll
  for (int s = 0; s < NS; s++) {
    #pragma unroll
    for (int r = 0; r < 4; r++) {
      int row = row0 + mbase + (l >> 4) * 4 + r;
      int col = (wn * NS + s) * 16 + lrow;
      P8[((size_t)q * CCH + row) * N + col] = acc[s][r];
    }
  }
  if (SN2) {
    #pragma unroll
    for (int i = 0; i < AI; i++) {
      float s = acc2[i];
      s += __shfl_xor(s, 1, 8); s += __shfl_xor(s, 2, 8); s += __shfl_xor(s, 4, 8);
      if ((tid & 7) == 0) sn2[sidA[ar[i]]] = s;
    }
  }
}

// ---------- per-cluster epilogue: conc + logsumexp (deterministic tree reduces) ----------
template<int K>
__global__ __launch_bounds__(256) void k_fin(const float* __restrict__ P8,
    const float* __restrict__ sn2, const int* __restrict__ rs,
    const int* __restrict__ cnt, const int* __restrict__ off,
    double* __restrict__ clLoss) {
  __shared__ float pcc[4096];
  __shared__ float red[256];
  __shared__ double redd[256];
  __shared__ float s_conc;
  const int c = blockIdx.x;
  const int n = cnt[c], base = off[c];
  const int tid = threadIdx.x;
  float rn0 = 0.f;
  #pragma unroll
  for (int qq = 0; qq < 8; qq++) rn0 += sn2[rs[(size_t)base * 8 + qq]];
  // phase A: diagonal dots + conc numerator
  float t = 0.f;
  for (int r = tid; r < n; r += 256) {
    float pd = 0.f, rn = 0.f;
    #pragma unroll
    for (int qq = 0; qq < 8; qq++) {
      pd += P8[((size_t)qq * CCH + base + r) * K + c];
      rn += sn2[rs[(size_t)(base + r) * 8 + qq]];
    }
    pcc[r] = pd;
    if (r > 0) {
      float d2 = rn - 2.f * pd + rn0;
      t += (d2 > 0.f) ? sqrtf(d2) : 0.f;
    }
  }
  red[tid] = t; __syncthreads();
  for (int o = 128; o; o >>= 1) { if (tid < o) red[tid] += red[tid + o]; __syncthreads(); }
  if (tid == 0) s_conc = red[0] / ((float)n * logf((float)n + 10.f));
  __syncthreads();
  const float invc = 1.f / s_conc;
  // phase B: per-row logsumexp
  const int wv = tid >> 6, lane = tid & 63;
  const int sub = (K == 64) ? 0 : (lane >> 4);
  const int cc = lane & (K - 1);
  constexpr int RPI = (K == 64) ? 4 : 16;
  double acc = 0.0;
  for (int r = wv * (RPI / 4) + sub; r < n; r += RPI) {
    float s = 0.f;
    #pragma unroll
    for (int qq = 0; qq < 8; qq++) s += P8[((size_t)qq * CCH + base + r) * K + cc];
    float lg = s * invc;
    float m = lg;
    #pragma unroll
    for (int o = K / 2; o; o >>= 1) m = fmaxf(m, __shfl_xor(m, o, K));
    float e = expf(lg - m);
    float se = e;
    #pragma unroll
    for (int o = K / 2; o; o >>= 1) se += __shfl_xor(se, o, K);
    if (cc == 0) acc += (double)(m + logf(se)) - (double)(pcc[r] * invc);
  }
  redd[tid] = acc; __syncthreads();
  for (int o = 128; o; o >>= 1) { if (tid < o) redd[tid] += redd[tid + o]; __syncthreads(); }
  if (tid == 0) clLoss[c] = redd[0] / (double)n;
}

// ---------- final scalars ----------
__global__ void k_final(const double* __restrict__ cl0, const double* __restrict__ cl1,
                        float* __restrict__ out) {
  if (threadIdx.x == 0) {
    double s0 = 0.0, s1 = 0.0;
    for (int i = 0; i < 64; i++) s0 += cl0[i];
    for (int i = 0; i < 16; i++) s1 += cl1[i];
    out[0] = (float)(s0 / 4096.0);
    out[1] = (float)(s1 / 8192.0);
  }
}

extern "C" void kernel_launch(void* const* d_in, const int* in_sizes, int n_in,
                              void* d_out, int out_size, void* d_ws, size_t ws_size,
                              hipStream_t stream) {
  const float* X = (const float*)d_in[0];
  const int* im0 = (const int*)d_in[1];
  const int* im1 = (const int*)d_in[2];
  float* out = (float*)d_out;

  char* w = (char*)d_ws;
  auto alloc = [&](size_t bytes) -> char* {
    char* p = w; w += (bytes + 255) & ~(size_t)255; return p;
  };
  int*    cnt0  = (int*)alloc(64 * 4);
  int*    off0  = (int*)alloc(64 * 4);
  int*    cnt1  = (int*)alloc(16 * 4);
  int*    off1  = (int*)alloc(16 * 4);
  int*    mem0  = (int*)alloc((size_t)CCH * 4);
  int*    mem1  = (int*)alloc((size_t)CCH * 4);
  int*    rs0   = (int*)alloc((size_t)CCH * 8 * 4);
  int*    rs1   = (int*)alloc((size_t)CCH * 8 * 4);
  float*  sn2   = (float*)alloc((size_t)8 * CCH * 4);
  unsigned short* Brep0 = (unsigned short*)alloc((size_t)512 * SPADE * 2);
  unsigned short* Brep1 = (unsigned short*)alloc((size_t)128 * SPADE * 2);
  float*  P8_0  = (float*)alloc((size_t)8 * CCH * 64 * 4);
  float*  P8_1  = (float*)alloc((size_t)8 * CCH * 16 * 4);
  double* cl0   = (double*)alloc(64 * 8);
  double* cl1   = (double*)alloc(16 * 8);

  k_setup<<<80, 64, 0, stream>>>(im0, im1, cnt0, off0, cnt1, off1, mem0, mem1, rs0, rs1);
  k_brep<<<160, 256, 0, stream>>>(X, cnt0, off0, cnt1, off1, mem0, mem1,
                                  (unsigned int*)Brep0, (unsigned int*)Brep1);
  k_gemm<32, 64, true><<<dim3(CCH / 32, 8), 256, 0, stream>>>(X, Brep0, rs0, P8_0, sn2);
  k_gemm<64, 16, false><<<dim3(CCH / 64, 8), 256, 0, stream>>>(X, Brep1, rs1, P8_1, nullptr);
  k_fin<64><<<64, 256, 0, stream>>>(P8_0, sn2, rs0, cnt0, off0, cl0);
  k_fin<16><<<16, 256, 0, stream>>>(P8_1, sn2, rs1, cnt1, off1, cl1);
  k_final<<<1, 64, 0, stream>>>(cl0, cl1, out);
}